// Round 2
// baseline (1185.816 us; speedup 1.0000x reference)
//
#include <hip/hip_runtime.h>
#include <stdint.h>

typedef unsigned short u16;
typedef short short8 __attribute__((ext_vector_type(8)));
typedef float floatx4 __attribute__((ext_vector_type(4)));

__device__ __forceinline__ u16 f2bf(float f) {
  union { float f; unsigned u; } t; t.f = f;
  return (u16)((t.u + 0x7fffu + ((t.u >> 16) & 1u)) >> 16);
}
__device__ __forceinline__ float lo16(unsigned w) { union { unsigned u; float f; } t; t.u = w << 16; return t.f; }
__device__ __forceinline__ float hi16(unsigned w) { union { unsigned u; float f; } t; t.u = w & 0xffff0000u; return t.f; }
__device__ __forceinline__ void unpack8(uint4 v, float* f) {
  f[0]=lo16(v.x); f[1]=hi16(v.x); f[2]=lo16(v.y); f[3]=hi16(v.y);
  f[4]=lo16(v.z); f[5]=hi16(v.z); f[6]=lo16(v.w); f[7]=hi16(v.w);
}
__device__ __forceinline__ uint4 pack8(const u16* o) {
  uint4 v;
  v.x = (unsigned)o[0] | ((unsigned)o[1] << 16);
  v.y = (unsigned)o[2] | ((unsigned)o[3] << 16);
  v.z = (unsigned)o[4] | ((unsigned)o[5] << 16);
  v.w = (unsigned)o[6] | ((unsigned)o[7] << 16);
  return v;
}

// ---------------------------------------------------------------------------
// wconv: fp32 -> bf16 copy (in_proj_w only; 786432 elems)
// ---------------------------------------------------------------------------
__global__ __launch_bounds__(256)
void wconv(const float* __restrict__ src, u16* __restrict__ dst, int n4) {
  int i = blockIdx.x * 256 + threadIdx.x;
  if (i >= n4) return;
  float4 v = *(const float4*)(src + (size_t)i * 4);
  ushort4 o; o.x = f2bf(v.x); o.y = f2bf(v.y); o.z = f2bf(v.z); o.w = f2bf(v.w);
  *(ushort4*)(dst + (size_t)i * 4) = o;
}

// ---------------------------------------------------------------------------
// small_mm: C[512,512] = A[512,512(lda)] @ B[512,512]; fp32 in; OBF: bf16 out
// grid (32,32), 256 thr, one C element per thread (weight-fold GEMMs, tiny)
// ---------------------------------------------------------------------------
template<int OBF>
__global__ __launch_bounds__(256)
void small_mm(const float* __restrict__ A, int lda,
              const float* __restrict__ B, int ldb,
              void* __restrict__ Cv, int ldc) {
  int j = blockIdx.x * 16 + (threadIdx.x & 15);
  int i = blockIdx.y * 16 + (threadIdx.x >> 4);
  float s = 0.f;
#pragma unroll 4
  for (int k = 0; k < 512; ++k) s += A[(size_t)i * lda + k] * B[(size_t)k * ldb + j];
  if (OBF) ((u16*)Cv)[(size_t)i * ldc + j] = f2bf(s);
  else ((float*)Cv)[(size_t)i * ldc + j] = s;
}

// uv[i] = phw[i,:]@outb + phb[i]  (i<512) ; uv[512+i] = imw[i,:]@outb + imb[i]
__global__ __launch_bounds__(256)
void uv_kernel(const float* __restrict__ phw, const float* __restrict__ phb,
               const float* __restrict__ imw, const float* __restrict__ imb,
               const float* __restrict__ outb, float* __restrict__ uv) {
  int g = blockIdx.x * 256 + threadIdx.x;  // 0..1023
  int i = g & 511;
  const float* W = (g < 512) ? phw : imw;
  const float* bb = (g < 512) ? phb : imb;
  float s = bb[i];
#pragma unroll 4
  for (int c = 0; c < 512; ++c) s += W[(size_t)i * 512 + c] * outb[c];
  uv[g] = s;
}

// bcomb[i] = ob[i] + ow[i,:]@uv   (combined bias of the folded tail)
__global__ __launch_bounds__(256)
void bcomb_kernel(const float* __restrict__ ow, const float* __restrict__ ob,
                  const float* __restrict__ uv, float* __restrict__ bcomb) {
  int i = blockIdx.x * 256 + threadIdx.x;  // 0..511
  float s = ob[i];
#pragma unroll 4
  for (int r = 0; r < 1024; ++r) s += ow[(size_t)i * 1024 + r] * uv[r];
  bcomb[i] = s;
}

// ---------------------------------------------------------------------------
// build_xe: xe[(b*2048+t)*2+d][c] = bf16( x[b][c][d][t] + emb[d][c] )
// x fp32 (B,C,2,T); LDS transpose; xe bf16 (65536,512) staged in d_out.
// ---------------------------------------------------------------------------
__global__ __launch_bounds__(256)
void build_xe(const float* __restrict__ x, const float* __restrict__ emb,
              u16* __restrict__ xe) {
  __shared__ u16 tile[64][66];
  int bt = blockIdx.x;
  int tt = bt & 31, ct = (bt >> 5) & 7, d = (bt >> 8) & 1, b = bt >> 9;
  int t0 = tt * 64, c0 = ct * 64;
  int tid = threadIdx.x;
  int q = tid & 15, r = tid >> 4;  // q: 4-float t-chunk, r: c-row
#pragma unroll
  for (int p = 0; p < 4; ++p) {
    int c = p * 16 + r;
    const float* src = x + ((size_t)((b * 512 + c0 + c) * 2 + d)) * 2048 + t0 + q * 4;
    float4 v = *(const float4*)src;
    float e = emb[d * 512 + c0 + c];
    ushort4 o; o.x = f2bf(v.x + e); o.y = f2bf(v.y + e); o.z = f2bf(v.z + e); o.w = f2bf(v.w + e);
    *(ushort4*)&tile[c][q * 4] = o;
  }
  __syncthreads();
  int cq = tid & 7, tp = tid >> 3;
  int cc0 = cq * 8;
  u16 o0[8], o1[8];
#pragma unroll
  for (int i = 0; i < 8; ++i) {
    unsigned w2 = *(const unsigned*)&tile[cc0 + i][2 * tp];
    o0[i] = (u16)(w2 & 0xffffu); o1[i] = (u16)(w2 >> 16);
  }
  size_t n = (size_t)b * 2048 + t0 + 2 * tp;
  *(uint4*)(xe + (n * 2 + d) * 512 + c0 + cc0) = pack8(o0);
  *(uint4*)(xe + ((n + 1) * 2 + d) * 512 + c0 + cc0) = pack8(o1);
}

// ---------------------------------------------------------------------------
// qk_score: per (head h, 64-row tile): Q,K tiles via MFMA (64x256x512),
// then 2x2 softmax from LDS -> P[n][h][i][j] (fp32) + asum accumulation.
// Never materializes qkv in HBM.
// ---------------------------------------------------------------------------
__global__ __launch_bounds__(256, 2)
void qk_score(const u16* __restrict__ xe, const u16* __restrict__ inwb,
              const float* __restrict__ inb, float* __restrict__ P,
              float* __restrict__ asum) {
  __shared__ u16 smem[23040];            // 46,080 B; As 64x72, Bs 256x72; QK aliases
  u16* As = smem;                        // 4608 u16
  u16* Bs = smem + 4608;                 // 18432 u16
  int h = blockIdx.x;
  int m0 = blockIdx.y * 64;
  int t = threadIdx.x;
  int lane = t & 63, w = t >> 6;
  int wn = w * 64;                       // wave tile: 64(m) x 64(n) of 64x256
  int l15 = lane & 15, quad = lane >> 4;

  floatx4 acc[4][4];
#pragma unroll
  for (int i = 0; i < 4; ++i)
#pragma unroll
    for (int j = 0; j < 4; ++j) acc[i][j] = (floatx4){0.f, 0.f, 0.f, 0.f};

  int row = t >> 3;            // 0..31
  int cc = (t & 7) * 8;
  const u16* ga = xe + (size_t)(m0 + row) * 512 + cc;
  const u16* gbase = inwb + cc;
  int grow[8];
#pragma unroll
  for (int jb = 0; jb < 8; ++jb) {
    int brow = row + jb * 32;            // 0..255: <128 -> q rows, else k rows
    grow[jb] = (brow < 128) ? (h * 128 + brow) : (384 + h * 128 + brow);
  }
  uint4 ra[2], rb[8];
#pragma unroll
  for (int ja = 0; ja < 2; ++ja) ra[ja] = *(const uint4*)(ga + (size_t)(ja * 32) * 512);
#pragma unroll
  for (int jb = 0; jb < 8; ++jb) rb[jb] = *(const uint4*)(gbase + (size_t)grow[jb] * 512);

  for (int kt = 0; kt < 8; ++kt) {
#pragma unroll
    for (int ja = 0; ja < 2; ++ja) *(uint4*)&As[(row + ja * 32) * 72 + cc] = ra[ja];
#pragma unroll
    for (int jb = 0; jb < 8; ++jb) *(uint4*)&Bs[(row + jb * 32) * 72 + cc] = rb[jb];
    __syncthreads();
    if (kt < 7) {
      int o = (kt + 1) * 64;
#pragma unroll
      for (int ja = 0; ja < 2; ++ja) ra[ja] = *(const uint4*)(ga + (size_t)(ja * 32) * 512 + o);
#pragma unroll
      for (int jb = 0; jb < 8; ++jb) rb[jb] = *(const uint4*)(gbase + (size_t)grow[jb] * 512 + o);
    }
#pragma unroll
    for (int ki = 0; ki < 2; ++ki) {
      short8 af[4], bfv[4];
#pragma unroll
      for (int i = 0; i < 4; ++i)
        af[i] = *(const short8*)&As[(i * 16 + l15) * 72 + ki * 32 + quad * 8];
#pragma unroll
      for (int j = 0; j < 4; ++j)
        bfv[j] = *(const short8*)&Bs[(wn + j * 16 + l15) * 72 + ki * 32 + quad * 8];
#pragma unroll
      for (int i = 0; i < 4; ++i)
#pragma unroll
        for (int j = 0; j < 4; ++j)
          acc[i][j] = __builtin_amdgcn_mfma_f32_16x16x32_bf16(af[i], bfv[j], acc[i][j], 0, 0, 0);
    }
    __syncthreads();
  }

  // dump q,k (+bias) into QK[2][64][136] (aliases As/Bs; safe after last barrier)
  u16* QK = smem;
#pragma unroll
  for (int i = 0; i < 4; ++i) {
    int rrow = i * 16 + quad * 4;
#pragma unroll
    for (int j = 0; j < 4; ++j) {
      int col = wn + j * 16 + l15;       // 0..255; <128 = q col, else k col
      int sel = col >> 7, c = col & 127;
      float bv = inb[sel * 512 + h * 128 + c];
#pragma unroll
      for (int r = 0; r < 4; ++r)
        QK[(sel * 64 + rrow + r) * 136 + c] = f2bf(acc[i][j][r] + bv);
    }
  }
  __syncthreads();

  if (t < 64) {                          // 32 pairs x 2 query-devs
    const u16* qrow = &QK[t * 136];
    const u16* k0 = &QK[(64 + (t & ~1)) * 136];
    const u16* k1 = k0 + 136;
    float s0 = 0.f, s1 = 0.f;
#pragma unroll
    for (int c = 0; c < 128; c += 8) {
      float fq[8], f0[8], f1[8];
      unpack8(*(const uint4*)(qrow + c), fq);
      unpack8(*(const uint4*)(k0 + c), f0);
      unpack8(*(const uint4*)(k1 + c), f1);
#pragma unroll
      for (int u = 0; u < 8; ++u) { s0 += fq[u] * f0[u]; s1 += fq[u] * f1[u]; }
    }
    const float sc = 0.08838834764831845f;  // 1/sqrt(128)
    s0 *= sc; s1 *= sc;
    float mx = fmaxf(s0, s1);
    float e0 = __expf(s0 - mx), e1 = __expf(s1 - mx);
    float inv = 1.f / (e0 + e1);
    float p0 = e0 * inv, p1 = e1 * inv;
    int p = t >> 1, i = t & 1;
    int n = (m0 >> 1) + p;
    float2 st; st.x = p0; st.y = p1;
    *(float2*)&P[((size_t)n * 4 + h) * 4 + i * 2] = st;
    // wave-reduce over same-parity lanes (parity == i)
    float v0 = p0, v1 = p1;
    v0 += __shfl_down(v0, 32, 64); v1 += __shfl_down(v1, 32, 64);
    v0 += __shfl_down(v0, 16, 64); v1 += __shfl_down(v1, 16, 64);
    v0 += __shfl_down(v0, 8, 64);  v1 += __shfl_down(v1, 8, 64);
    v0 += __shfl_down(v0, 4, 64);  v1 += __shfl_down(v1, 4, 64);
    v0 += __shfl_down(v0, 2, 64);  v1 += __shfl_down(v1, 2, 64);
    if (t < 2) {
      int b = m0 >> 12;
      atomicAdd(&asum[b * 4 + i * 2 + 0], v0);
      atomicAdd(&asum[b * 4 + i * 2 + 1], v1);
    }
  }
}

// ---------------------------------------------------------------------------
// gemm_bt: C[M,N] = A[M,K] @ B[N,K]^T + bias; bf16 A/B, fp32 bias/acc.
// EPI 1: fp32 out, transposed write to (B,C,T):  C[((m>>11)*ldc+n)*2048 + (m&2047)]
// EPI 2: bf16 out with 2x2 P-mix across device-row pairs (v_ctx);  h = blockIdx.x
// ---------------------------------------------------------------------------
template<int EPI>
__global__ __launch_bounds__(256, 2)
void gemm_bt(const u16* __restrict__ A, int lda,
             const u16* __restrict__ B, int ldb,
             const float* __restrict__ bias,
             void* __restrict__ Cv, int ldc, int K,
             const float* __restrict__ P) {
  const int LSTR = 72;
  __shared__ u16 As[128 * 72];
  __shared__ u16 Bs[128 * 72];
  int m0 = blockIdx.y * 128;
  int n0 = blockIdx.x * 128;
  int t = threadIdx.x;
  int lane = t & 63;
  int w = t >> 6;
  int wm = (w >> 1) * 64, wn = (w & 1) * 64;
  int l15 = lane & 15, quad = lane >> 4;

  floatx4 acc[4][4];
#pragma unroll
  for (int i = 0; i < 4; ++i)
#pragma unroll
    for (int j = 0; j < 4; ++j) acc[i][j] = (floatx4){0.f, 0.f, 0.f, 0.f};

  int row = t >> 3;
  int cc = (t & 7) * 8;
  const u16* ga = A + (size_t)(m0 + row) * lda + cc;
  const u16* gb = B + (size_t)(n0 + row) * ldb + cc;

  uint4 ra[4], rb[4];
#pragma unroll
  for (int j = 0; j < 4; ++j) {
    ra[j] = *(const uint4*)(ga + (size_t)(j * 32) * lda);
    rb[j] = *(const uint4*)(gb + (size_t)(j * 32) * ldb);
  }
  int KT = K >> 6;
  for (int kt = 0; kt < KT; ++kt) {
#pragma unroll
    for (int j = 0; j < 4; ++j) {
      *(uint4*)&As[(row + j * 32) * LSTR + cc] = ra[j];
      *(uint4*)&Bs[(row + j * 32) * LSTR + cc] = rb[j];
    }
    __syncthreads();
    if (kt + 1 < KT) {
      const u16* ga2 = ga + (kt + 1) * 64;
      const u16* gb2 = gb + (kt + 1) * 64;
#pragma unroll
      for (int j = 0; j < 4; ++j) {
        ra[j] = *(const uint4*)(ga2 + (size_t)(j * 32) * lda);
        rb[j] = *(const uint4*)(gb2 + (size_t)(j * 32) * ldb);
      }
    }
#pragma unroll
    for (int ki = 0; ki < 2; ++ki) {
      short8 af[4], bfv[4];
#pragma unroll
      for (int i = 0; i < 4; ++i)
        af[i] = *(const short8*)&As[(wm + i * 16 + l15) * LSTR + ki * 32 + quad * 8];
#pragma unroll
      for (int j = 0; j < 4; ++j)
        bfv[j] = *(const short8*)&Bs[(wn + j * 16 + l15) * LSTR + ki * 32 + quad * 8];
#pragma unroll
      for (int i = 0; i < 4; ++i)
#pragma unroll
        for (int j = 0; j < 4; ++j)
          acc[i][j] = __builtin_amdgcn_mfma_f32_16x16x32_bf16(af[i], bfv[j], acc[i][j], 0, 0, 0);
    }
    __syncthreads();
  }

  // epilogue: C/D layout col = lane&15, row = quad*4 + reg  [m89-verified]
#pragma unroll
  for (int i = 0; i < 4; ++i) {
    int mrow = m0 + wm + i * 16 + quad * 4;
    float4 P0, P1;
    if (EPI == 2) {
      int np0 = mrow >> 1;
      P0 = *(const float4*)&P[((size_t)np0 * 4 + blockIdx.x) * 4];
      P1 = *(const float4*)&P[((size_t)(np0 + 1) * 4 + blockIdx.x) * 4];
    }
#pragma unroll
    for (int j = 0; j < 4; ++j) {
      int col = n0 + wn + j * 16 + l15;
      float bv = bias[col];
      floatx4 a = acc[i][j];
      if (EPI == 1) {
        int bb = mrow >> 11, ti = mrow & 2047;
        float4 o; o.x = a[0] + bv; o.y = a[1] + bv; o.z = a[2] + bv; o.w = a[3] + bv;
        *(float4*)&((float*)Cv)[((size_t)bb * ldc + col) * 2048 + ti] = o;
      } else if (EPI == 2) {
        float a0 = a[0] + bv, a1 = a[1] + bv, a2 = a[2] + bv, a3 = a[3] + bv;
        u16* C = (u16*)Cv;
        C[(size_t)(mrow + 0) * ldc + col] = f2bf(P0.x * a0 + P0.y * a1);
        C[(size_t)(mrow + 1) * ldc + col] = f2bf(P0.z * a0 + P0.w * a1);
        C[(size_t)(mrow + 2) * ldc + col] = f2bf(P1.x * a2 + P1.y * a3);
        C[(size_t)(mrow + 3) * ldc + col] = f2bf(P1.z * a2 + P1.w * a3);
      } else {
        u16* C = (u16*)Cv;
#pragma unroll
        for (int r = 0; r < 4; ++r)
          C[(size_t)(mrow + r) * ldc + col] = f2bf(a[r] + bv);
      }
    }
  }
}

__global__ void avg_kernel(const float* __restrict__ asum, float* __restrict__ out) {
  int i = threadIdx.x;  // 64 = 16 b * 4
  out[16777216 + i] = asum[i] * (1.0f / 8192.0f);  // / (H=4 * T=2048)
}

// ---------------------------------------------------------------------------
// Workspace (~70.5 MiB):
//   [0, 64Mi)            ctx  (bf16 65536x512)
//   +64Mi  (1,572,864 B) inw_bf (bf16 1536x512)
//   then Wcomb (bf16 512x1024), T1/T2 (fp32 512x512), uv(1024f), bcomb(512f),
//   P (fp32 32768x4x2x2), asum (64f)
// xe (bf16 65536x512 = 64 MiB) staged in d_out main region (dead before final GEMM).
// ---------------------------------------------------------------------------
extern "C" void kernel_launch(void* const* d_in, const int* in_sizes, int n_in,
                              void* d_out, int out_size, void* d_ws, size_t ws_size,
                              hipStream_t stream) {
  const float* x    = (const float*)d_in[0];   // (16,512,2,2048)
  const float* emb  = (const float*)d_in[1];   // (1,2,512)
  const float* inw  = (const float*)d_in[2];   // (1536,512)
  const float* inb  = (const float*)d_in[3];   // (1536)
  const float* outw = (const float*)d_in[4];   // (512,512)
  const float* outb = (const float*)d_in[5];
  const float* phw  = (const float*)d_in[6];
  const float* phb  = (const float*)d_in[7];
  const float* imw  = (const float*)d_in[8];
  const float* imb  = (const float*)d_in[9];
  const float* ow   = (const float*)d_in[10];  // (512,1024)
  const float* ob   = (const float*)d_in[11];
  float* outF = (float*)d_out;

  char* wsb = (char*)d_ws;
  u16*   ctx    = (u16*)wsb;                               //  0        .. 67,108,864
  u16*   inw_bf = (u16*)(wsb + 67108864);                  // +1,572,864
  u16*   Wcomb  = (u16*)(wsb + 68681728);                  // +1,048,576
  float* T1     = (float*)(wsb + 69730304);                // +1,048,576
  float* T2     = (float*)(wsb + 70778880);                // +1,048,576
  float* uv     = (float*)(wsb + 71827456);                // +4,096
  float* bcomb  = (float*)(wsb + 71831552);                // +2,048
  float* P      = (float*)(wsb + 71833600);                // +2,097,152
  float* asum   = (float*)(wsb + 73930752);                // +256
  u16*   xe     = (u16*)d_out;                             // 64 MiB scratch in d_out

  // weight prep (tiny)
  wconv<<<768, 256, 0, stream>>>(inw, inw_bf, 196608);
  small_mm<0><<<dim3(32, 32), 256, 0, stream>>>(phw, 512, outw, 512, T1, 512);
  small_mm<0><<<dim3(32, 32), 256, 0, stream>>>(imw, 512, outw, 512, T2, 512);
  small_mm<1><<<dim3(32, 32), 256, 0, stream>>>(ow, 1024, T1, 512, Wcomb, 1024);
  small_mm<1><<<dim3(32, 32), 256, 0, stream>>>(ow + 512, 1024, T2, 512, Wcomb + 512, 1024);
  uv_kernel<<<4, 256, 0, stream>>>(phw, phb, imw, imb, outb, uv);
  bcomb_kernel<<<2, 256, 0, stream>>>(ow, ob, uv, bcomb);

  // xe = transpose(x) + emb  (bf16, staged in d_out)
  build_xe<<<8192, 256, 0, stream>>>(x, emb, xe);

  hipMemsetAsync(asum, 0, 64 * sizeof(float), stream);
  // Q/K MFMA + 2x2 softmax -> P, asum
  qk_score<<<dim3(4, 1024), 256, 0, stream>>>(xe, inw_bf, inb, P, asum);
  // V GEMM + P-mix epilogue -> ctx  (A=xe, B=v-weights rows 1024..1535)
  gemm_bt<2><<<dim3(4, 512), 256, 0, stream>>>(xe, 512, inw_bf + 524288, 512,
                                               inb + 1024, ctx, 512, 512, P);
  // folded tail: out = ctx(pairs, K=1024) @ Wcomb^T + bcomb, transposed (B,C,T)
  gemm_bt<1><<<dim3(4, 256), 256, 0, stream>>>(ctx, 1024, Wcomb, 1024,
                                               bcomb, outF, 512, 1024, nullptr);
  avg_kernel<<<1, 64, 0, stream>>>(asum, outF);
}

// Round 3
// 770.103 us; speedup vs baseline: 1.5398x; 1.5398x over previous
//
#include <hip/hip_runtime.h>
#include <stdint.h>

typedef unsigned short u16;
typedef short short8 __attribute__((ext_vector_type(8)));
typedef float floatx4 __attribute__((ext_vector_type(4)));

__device__ __forceinline__ u16 f2bf(float f) {
  union { float f; unsigned u; } t; t.f = f;
  return (u16)((t.u + 0x7fffu + ((t.u >> 16) & 1u)) >> 16);
}
__device__ __forceinline__ float lo16(unsigned w) { union { unsigned u; float f; } t; t.u = w << 16; return t.f; }
__device__ __forceinline__ float hi16(unsigned w) { union { unsigned u; float f; } t; t.u = w & 0xffff0000u; return t.f; }
__device__ __forceinline__ void unpack8(uint4 v, float* f) {
  f[0]=lo16(v.x); f[1]=hi16(v.x); f[2]=lo16(v.y); f[3]=hi16(v.y);
  f[4]=lo16(v.z); f[5]=hi16(v.z); f[6]=lo16(v.w); f[7]=hi16(v.w);
}
__device__ __forceinline__ uint4 pack8(const u16* o) {
  uint4 v;
  v.x = (unsigned)o[0] | ((unsigned)o[1] << 16);
  v.y = (unsigned)o[2] | ((unsigned)o[3] << 16);
  v.z = (unsigned)o[4] | ((unsigned)o[5] << 16);
  v.w = (unsigned)o[6] | ((unsigned)o[7] << 16);
  return v;
}

// async global->LDS, 16B per lane; lds dst is wave-uniform base + lane*16
__device__ __forceinline__ void gll16(const void* g, void* l) {
  __builtin_amdgcn_global_load_lds(
      (const __attribute__((address_space(1))) void*)(uintptr_t)(g),
      (__attribute__((address_space(3))) void*)(unsigned)(uintptr_t)(l),
      16, 0, 0);
}

// ---------------------------------------------------------------------------
// wconv: fp32 -> bf16 copy (in_proj_w; 786432 elems = 196608 x4)
// ---------------------------------------------------------------------------
__global__ __launch_bounds__(256)
void wconv(const float* __restrict__ src, u16* __restrict__ dst, int n4) {
  int i = blockIdx.x * 256 + threadIdx.x;
  if (i >= n4) return;
  float4 v = *(const float4*)(src + (size_t)i * 4);
  ushort4 o; o.x = f2bf(v.x); o.y = f2bf(v.y); o.z = f2bf(v.z); o.w = f2bf(v.w);
  *(ushort4*)(dst + (size_t)i * 4) = o;
}

// ---------------------------------------------------------------------------
// small_mm: C[512,512] = A[512,512(lda)] @ B[512,512]; fp32 in; OBF: bf16 out
// ---------------------------------------------------------------------------
template<int OBF>
__global__ __launch_bounds__(256)
void small_mm(const float* __restrict__ A, int lda,
              const float* __restrict__ B, int ldb,
              void* __restrict__ Cv, int ldc) {
  int j = blockIdx.x * 16 + (threadIdx.x & 15);
  int i = blockIdx.y * 16 + (threadIdx.x >> 4);
  float s = 0.f;
#pragma unroll 4
  for (int k = 0; k < 512; ++k) s += A[(size_t)i * lda + k] * B[(size_t)k * ldb + j];
  if (OBF) ((u16*)Cv)[(size_t)i * ldc + j] = f2bf(s);
  else ((float*)Cv)[(size_t)i * ldc + j] = s;
}

__global__ __launch_bounds__(256)
void uv_kernel(const float* __restrict__ phw, const float* __restrict__ phb,
               const float* __restrict__ imw, const float* __restrict__ imb,
               const float* __restrict__ outb, float* __restrict__ uv) {
  int g = blockIdx.x * 256 + threadIdx.x;  // 0..1023
  int i = g & 511;
  const float* W = (g < 512) ? phw : imw;
  const float* bb = (g < 512) ? phb : imb;
  float s = bb[i];
#pragma unroll 4
  for (int c = 0; c < 512; ++c) s += W[(size_t)i * 512 + c] * outb[c];
  uv[g] = s;
}

__global__ __launch_bounds__(256)
void bcomb_kernel(const float* __restrict__ ow, const float* __restrict__ ob,
                  const float* __restrict__ uv, float* __restrict__ bcomb) {
  int i = blockIdx.x * 256 + threadIdx.x;  // 0..511
  float s = ob[i];
#pragma unroll 4
  for (int r = 0; r < 1024; ++r) s += ow[(size_t)i * 1024 + r] * uv[r];
  bcomb[i] = s;
}

// ---------------------------------------------------------------------------
// build_xe: xe[(b*2048+t)*2+d][c] = bf16( x[b][c][d][t] + emb[d][c] )
// ---------------------------------------------------------------------------
__global__ __launch_bounds__(256)
void build_xe(const float* __restrict__ x, const float* __restrict__ emb,
              u16* __restrict__ xe) {
  __shared__ u16 tile[64][66];
  int bt = blockIdx.x;
  int tt = bt & 31, ct = (bt >> 5) & 7, d = (bt >> 8) & 1, b = bt >> 9;
  int t0 = tt * 64, c0 = ct * 64;
  int tid = threadIdx.x;
  int q = tid & 15, r = tid >> 4;
#pragma unroll
  for (int p = 0; p < 4; ++p) {
    int c = p * 16 + r;
    const float* src = x + ((size_t)((b * 512 + c0 + c) * 2 + d)) * 2048 + t0 + q * 4;
    float4 v = *(const float4*)src;
    float e = emb[d * 512 + c0 + c];
    ushort4 o; o.x = f2bf(v.x + e); o.y = f2bf(v.y + e); o.z = f2bf(v.z + e); o.w = f2bf(v.w + e);
    *(ushort4*)&tile[c][q * 4] = o;
  }
  __syncthreads();
  int cq = tid & 7, tp = tid >> 3;
  int cc0 = cq * 8;
  u16 o0[8], o1[8];
#pragma unroll
  for (int i = 0; i < 8; ++i) {
    unsigned w2 = *(const unsigned*)&tile[cc0 + i][2 * tp];
    o0[i] = (u16)(w2 & 0xffffu); o1[i] = (u16)(w2 >> 16);
  }
  size_t n = (size_t)b * 2048 + t0 + 2 * tp;
  *(uint4*)(xe + (n * 2 + d) * 512 + c0 + cc0) = pack8(o0);
  *(uint4*)(xe + ((n + 1) * 2 + d) * 512 + c0 + cc0) = pack8(o1);
}

// ---------------------------------------------------------------------------
// gemm_bt: C[M,N] = A[M,K] @ B[N,K]^T + bias; bf16 A/B, fp32 bias, fp32 acc.
// global_load_lds staging (unpadded LDS 128x64), 128x128 tile, BK=64.
// EPI 0: bf16 out.
// EPI 1: fp32 out, transposed write to (B,C,T).
// EPI 2: bf16 out, 2x2 P-mix across device-row pairs; h = blockIdx.x.
// ---------------------------------------------------------------------------
template<int EPI>
__global__ __launch_bounds__(256, 2)
void gemm_bt(const u16* __restrict__ A, int lda,
             const u16* __restrict__ B, int ldb,
             const float* __restrict__ bias,
             void* __restrict__ Cv, int ldc, int K,
             const float* __restrict__ P) {
  __shared__ u16 As[128 * 64];
  __shared__ u16 Bs[128 * 64];
  int m0 = blockIdx.y * 128;
  int n0 = blockIdx.x * 128;
  int t = threadIdx.x;
  int lane = t & 63;
  int w = t >> 6;
  int wm = (w >> 1) * 64, wn = (w & 1) * 64;
  int l15 = lane & 15, quad = lane >> 4;

  floatx4 acc[4][4];
#pragma unroll
  for (int i = 0; i < 4; ++i)
#pragma unroll
    for (int j = 0; j < 4; ++j) acc[i][j] = (floatx4){0.f, 0.f, 0.f, 0.f};

  // staging: wave w owns rows [w*32, w*32+32); 4 issues of 8 rows each side.
  int lrow = lane >> 3, lcol = (lane & 7) * 8;
  const u16* gA = A + (size_t)(m0 + w * 32 + lrow) * lda + lcol;
  const u16* gB = B + (size_t)(n0 + w * 32 + lrow) * ldb + lcol;
  u16* lA = As + (w * 32) * 64;
  u16* lB = Bs + (w * 32) * 64;

  int KT = K >> 6;
  for (int kt = 0; kt < KT; ++kt) {
    int ko = kt * 64;
#pragma unroll
    for (int j = 0; j < 4; ++j) {
      gll16(gA + (size_t)(j * 8) * lda + ko, lA + (j * 8) * 64);
      gll16(gB + (size_t)(j * 8) * ldb + ko, lB + (j * 8) * 64);
    }
    __syncthreads();
#pragma unroll
    for (int ki = 0; ki < 2; ++ki) {
      short8 af[4], bfv[4];
#pragma unroll
      for (int i = 0; i < 4; ++i)
        af[i] = *(const short8*)&As[(wm + i * 16 + l15) * 64 + ki * 32 + quad * 8];
#pragma unroll
      for (int j = 0; j < 4; ++j)
        bfv[j] = *(const short8*)&Bs[(wn + j * 16 + l15) * 64 + ki * 32 + quad * 8];
#pragma unroll
      for (int i = 0; i < 4; ++i)
#pragma unroll
        for (int j = 0; j < 4; ++j)
          acc[i][j] = __builtin_amdgcn_mfma_f32_16x16x32_bf16(af[i], bfv[j], acc[i][j], 0, 0, 0);
    }
    __syncthreads();
  }

  // epilogue: C/D layout col = lane&15, row = quad*4 + reg  [m89-verified]
#pragma unroll
  for (int i = 0; i < 4; ++i) {
    int mrow = m0 + wm + i * 16 + quad * 4;
    float4 P0, P1;
    if (EPI == 2) {
      int np0 = mrow >> 1;
      P0 = *(const float4*)&P[((size_t)np0 * 4 + blockIdx.x) * 4];
      P1 = *(const float4*)&P[((size_t)(np0 + 1) * 4 + blockIdx.x) * 4];
    }
#pragma unroll
    for (int j = 0; j < 4; ++j) {
      int col = n0 + wn + j * 16 + l15;
      float bv = bias[col];
      floatx4 a = acc[i][j];
      if (EPI == 1) {
        int bb = mrow >> 11, ti = mrow & 2047;
        float4 o; o.x = a[0] + bv; o.y = a[1] + bv; o.z = a[2] + bv; o.w = a[3] + bv;
        *(float4*)&((float*)Cv)[((size_t)bb * ldc + col) * 2048 + ti] = o;
      } else if (EPI == 2) {
        float a0 = a[0] + bv, a1 = a[1] + bv, a2 = a[2] + bv, a3 = a[3] + bv;
        u16* C = (u16*)Cv;
        C[(size_t)(mrow + 0) * ldc + col] = f2bf(P0.x * a0 + P0.y * a1);
        C[(size_t)(mrow + 1) * ldc + col] = f2bf(P0.z * a0 + P0.w * a1);
        C[(size_t)(mrow + 2) * ldc + col] = f2bf(P1.x * a2 + P1.y * a3);
        C[(size_t)(mrow + 3) * ldc + col] = f2bf(P1.z * a2 + P1.w * a3);
      } else {
        u16* C = (u16*)Cv;
#pragma unroll
        for (int r = 0; r < 4; ++r)
          C[(size_t)(mrow + r) * ldc + col] = f2bf(a[r] + bv);
      }
    }
  }
}

// ---------------------------------------------------------------------------
// score_kernel: thread per (n,h); QK row 2n/2n+1, q at col h*128, k at 512+h*128.
// 2x2 scores -> softmax -> P[n][h][2][2] (float4) + asum block reduction.
// ---------------------------------------------------------------------------
__global__ __launch_bounds__(256)
void score_kernel(const u16* __restrict__ QK, float* __restrict__ P,
                  float* __restrict__ asum) {
  int g = blockIdx.x * 256 + threadIdx.x;
  int n = g >> 2, h = g & 3;
  const u16* q0 = QK + (size_t)(2 * n) * 1024 + h * 128;
  const u16* q1 = q0 + 1024;
  const u16* k0 = q0 + 512;
  const u16* k1 = k0 + 1024;

  float s00 = 0.f, s01 = 0.f, s10 = 0.f, s11 = 0.f;
#pragma unroll
  for (int c = 0; c < 128; c += 8) {
    float fq0[8], fq1[8], fk0[8], fk1[8];
    unpack8(*(const uint4*)(q0 + c), fq0);
    unpack8(*(const uint4*)(q1 + c), fq1);
    unpack8(*(const uint4*)(k0 + c), fk0);
    unpack8(*(const uint4*)(k1 + c), fk1);
#pragma unroll
    for (int u = 0; u < 8; ++u) {
      s00 += fq0[u] * fk0[u]; s01 += fq0[u] * fk1[u];
      s10 += fq1[u] * fk0[u]; s11 += fq1[u] * fk1[u];
    }
  }
  const float sc = 0.08838834764831845f;  // 1/sqrt(128)
  s00 *= sc; s01 *= sc; s10 *= sc; s11 *= sc;
  float m0v = fmaxf(s00, s01), m1v = fmaxf(s10, s11);
  float e00 = __expf(s00 - m0v), e01 = __expf(s01 - m0v);
  float e10 = __expf(s10 - m1v), e11 = __expf(s11 - m1v);
  float i0 = 1.f / (e00 + e01), i1 = 1.f / (e10 + e11);
  float4 p; p.x = e00 * i0; p.y = e01 * i0; p.z = e10 * i1; p.w = e11 * i1;
  *(float4*)&P[(size_t)g * 4] = p;

  float pv[4] = {p.x, p.y, p.z, p.w};
#pragma unroll
  for (int k2 = 0; k2 < 4; ++k2) {
    float v = pv[k2];
    v += __shfl_down(v, 32, 64); v += __shfl_down(v, 16, 64);
    v += __shfl_down(v, 8, 64);  v += __shfl_down(v, 4, 64);
    v += __shfl_down(v, 2, 64);  v += __shfl_down(v, 1, 64);
    pv[k2] = v;
  }
  __shared__ float red[4][4];
  int lane = threadIdx.x & 63, wv = threadIdx.x >> 6;
  if (lane == 0) { red[wv][0] = pv[0]; red[wv][1] = pv[1]; red[wv][2] = pv[2]; red[wv][3] = pv[3]; }
  __syncthreads();
  if (threadIdx.x < 4) {
    float s = red[0][threadIdx.x] + red[1][threadIdx.x] + red[2][threadIdx.x] + red[3][threadIdx.x];
    int b = (blockIdx.x * 64) >> 11;
    atomicAdd(&asum[b * 4 + threadIdx.x], s);
  }
}

__global__ void avg_kernel(const float* __restrict__ asum, float* __restrict__ out) {
  int i = threadIdx.x;  // 64 = 16 b * 4
  out[16777216 + i] = asum[i] * (1.0f / 8192.0f);  // / (H=4 * T=2048)
}

// ---------------------------------------------------------------------------
// Workspace (~208 MiB; round-0 ran with 268 MiB of ws writes -> safe):
//   ctx    bf16 65536x512   @ 0           (64 MiB)
//   QK     bf16 65536x1024  @ 67108864    (128 MiB)
//   inw_bf bf16 1536x512    @ 201326592   (1.5 MiB)
//   Wcomb  bf16 512x1024    @ 202899456   (1 MiB)
//   T1,T2  fp32 512x512     @ 203948032 / 204996608
//   uv(4KiB) @206045184, bcomb(2KiB) @206049280, P fp32 @206051328 (2 MiB),
//   asum @208148480
// xe (bf16 65536x512 = 64 MiB) staged in d_out (dead before final GEMM writes).
// ---------------------------------------------------------------------------
extern "C" void kernel_launch(void* const* d_in, const int* in_sizes, int n_in,
                              void* d_out, int out_size, void* d_ws, size_t ws_size,
                              hipStream_t stream) {
  const float* x    = (const float*)d_in[0];
  const float* emb  = (const float*)d_in[1];
  const float* inw  = (const float*)d_in[2];
  const float* inb  = (const float*)d_in[3];
  const float* outw = (const float*)d_in[4];
  const float* outb = (const float*)d_in[5];
  const float* phw  = (const float*)d_in[6];
  const float* phb  = (const float*)d_in[7];
  const float* imw  = (const float*)d_in[8];
  const float* imb  = (const float*)d_in[9];
  const float* ow   = (const float*)d_in[10];
  const float* ob   = (const float*)d_in[11];
  float* outF = (float*)d_out;

  char* wsb = (char*)d_ws;
  u16*   ctx    = (u16*)wsb;
  u16*   QK     = (u16*)(wsb + 67108864);
  u16*   inw_bf = (u16*)(wsb + 201326592);
  u16*   Wcomb  = (u16*)(wsb + 202899456);
  float* T1     = (float*)(wsb + 203948032);
  float* T2     = (float*)(wsb + 204996608);
  float* uv     = (float*)(wsb + 206045184);
  float* bcomb  = (float*)(wsb + 206049280);
  float* P      = (float*)(wsb + 206051328);
  float* asum   = (float*)(wsb + 208148480);
  u16*   xe     = (u16*)d_out;

  // weight prep (tiny)
  wconv<<<768, 256, 0, stream>>>(inw, inw_bf, 196608);
  small_mm<0><<<dim3(32, 32), 256, 0, stream>>>(phw, 512, outw, 512, T1, 512);
  small_mm<0><<<dim3(32, 32), 256, 0, stream>>>(imw, 512, outw, 512, T2, 512);
  small_mm<1><<<dim3(32, 32), 256, 0, stream>>>(ow, 1024, T1, 512, Wcomb, 1024);
  small_mm<1><<<dim3(32, 32), 256, 0, stream>>>(ow + 512, 1024, T2, 512, Wcomb + 512, 1024);
  uv_kernel<<<4, 256, 0, stream>>>(phw, phb, imw, imb, outb, uv);
  bcomb_kernel<<<2, 256, 0, stream>>>(ow, ob, uv, bcomb);

  // xe = transpose(x) + emb  (bf16, staged in d_out)
  build_xe<<<8192, 256, 0, stream>>>(x, emb, xe);

  hipMemsetAsync(asum, 0, 64 * sizeof(float), stream);

  // QK = xe @ [Wq;Wk]^T + [bq;bk]   (65536 x 1024 x 512)
  gemm_bt<0><<<dim3(8, 512), 256, 0, stream>>>(xe, 512, inw_bf, 512, inb,
                                               QK, 1024, 512, nullptr);
  // 2x2 softmax -> P, asum
  score_kernel<<<512, 256, 0, stream>>>(QK, P, asum);
  // V GEMM + P-mix epilogue -> ctx
  gemm_bt<2><<<dim3(4, 512), 256, 0, stream>>>(xe, 512, inw_bf + 524288, 512,
                                               inb + 1024, ctx, 512, 512, P);
  // folded tail: out = ctx(pairs, K=1024) @ Wcomb^T + bcomb, transposed (B,C,T)
  gemm_bt<1><<<dim3(4, 256), 256, 0, stream>>>(ctx, 1024, Wcomb, 1024,
                                               bcomb, outF, 512, 1024, nullptr);
  avg_kernel<<<1, 64, 0, stream>>>(asum, outF);
}

// Round 4
// 653.230 us; speedup vs baseline: 1.8153x; 1.1789x over previous
//
#include <hip/hip_runtime.h>
#include <stdint.h>

typedef unsigned short u16;
typedef short short8 __attribute__((ext_vector_type(8)));
typedef float floatx4 __attribute__((ext_vector_type(4)));

__device__ __forceinline__ u16 f2bf(float f) {
  union { float f; unsigned u; } t; t.f = f;
  return (u16)((t.u + 0x7fffu + ((t.u >> 16) & 1u)) >> 16);
}
__device__ __forceinline__ float lo16(unsigned w) { union { unsigned u; float f; } t; t.u = w << 16; return t.f; }
__device__ __forceinline__ float hi16(unsigned w) { union { unsigned u; float f; } t; t.u = w & 0xffff0000u; return t.f; }
__device__ __forceinline__ void unpack8(uint4 v, float* f) {
  f[0]=lo16(v.x); f[1]=hi16(v.x); f[2]=lo16(v.y); f[3]=hi16(v.y);
  f[4]=lo16(v.z); f[5]=hi16(v.z); f[6]=lo16(v.w); f[7]=hi16(v.w);
}
__device__ __forceinline__ uint4 pack8(const u16* o) {
  uint4 v;
  v.x = (unsigned)o[0] | ((unsigned)o[1] << 16);
  v.y = (unsigned)o[2] | ((unsigned)o[3] << 16);
  v.z = (unsigned)o[4] | ((unsigned)o[5] << 16);
  v.w = (unsigned)o[6] | ((unsigned)o[7] << 16);
  return v;
}

// async global->LDS, 16B per lane; lds dst is wave-uniform base + lane*16
__device__ __forceinline__ void gll16(const void* g, void* l) {
  __builtin_amdgcn_global_load_lds(
      (const __attribute__((address_space(1))) void*)(uintptr_t)(g),
      (__attribute__((address_space(3))) void*)(unsigned)(uintptr_t)(l),
      16, 0, 0);
}

// ---------------------------------------------------------------------------
// prep_convert: one launch for all weight conversions.
// y=0: inw fp32->bf16 (196608 x4)   y=1: phw (65536 x4)   y=2: imw (65536 x4)
// y=3: ow (131072 x4)               y=4: outwT[j][i] = bf16(outw[i][j])
// ---------------------------------------------------------------------------
__device__ __forceinline__ void cvt4(const float* s, u16* d, int g) {
  float4 v = *(const float4*)(s + (size_t)g * 4);
  ushort4 o; o.x = f2bf(v.x); o.y = f2bf(v.y); o.z = f2bf(v.z); o.w = f2bf(v.w);
  *(ushort4*)(d + (size_t)g * 4) = o;
}
__global__ __launch_bounds__(256)
void prep_convert(const float* __restrict__ inw, const float* __restrict__ phw,
                  const float* __restrict__ imw, const float* __restrict__ ow,
                  const float* __restrict__ outw,
                  u16* __restrict__ inw_bf, u16* __restrict__ phw_bf,
                  u16* __restrict__ imw_bf, u16* __restrict__ ow_bf,
                  u16* __restrict__ outwT) {
  int which = blockIdx.y;
  int g = blockIdx.x * 256 + threadIdx.x;
  if (which == 0) { if (g < 196608) cvt4(inw, inw_bf, g); }
  else if (which == 1) { if (g < 65536) cvt4(phw, phw_bf, g); }
  else if (which == 2) { if (g < 65536) cvt4(imw, imw_bf, g); }
  else if (which == 3) { if (g < 131072) cvt4(ow, ow_bf, g); }
  else {
    if (g < 65536) {
      int i0 = (g >> 9) * 4, j = g & 511;   // reads coalesced along j
      ushort4 o;
      o.x = f2bf(outw[(size_t)(i0 + 0) * 512 + j]);
      o.y = f2bf(outw[(size_t)(i0 + 1) * 512 + j]);
      o.z = f2bf(outw[(size_t)(i0 + 2) * 512 + j]);
      o.w = f2bf(outw[(size_t)(i0 + 3) * 512 + j]);
      outwT[(size_t)j * 512 + i0 + 0] = o.x;
      outwT[(size_t)j * 512 + i0 + 1] = o.y;
      outwT[(size_t)j * 512 + i0 + 2] = o.z;
      outwT[(size_t)j * 512 + i0 + 3] = o.w;
    }
  }
}

__global__ __launch_bounds__(256)
void uv_kernel(const float* __restrict__ phw, const float* __restrict__ phb,
               const float* __restrict__ imw, const float* __restrict__ imb,
               const float* __restrict__ outb, float* __restrict__ uv) {
  int g = blockIdx.x * 256 + threadIdx.x;  // 0..1023
  int i = g & 511;
  const float* W = (g < 512) ? phw : imw;
  const float* bb = (g < 512) ? phb : imb;
  float s = bb[i];
#pragma unroll 4
  for (int c = 0; c < 512; ++c) s += W[(size_t)i * 512 + c] * outb[c];
  uv[g] = s;
}

__global__ __launch_bounds__(256)
void bcomb_kernel(const float* __restrict__ ow, const float* __restrict__ ob,
                  const float* __restrict__ uv, float* __restrict__ bcomb) {
  int i = blockIdx.x * 256 + threadIdx.x;  // 0..511
  float s = ob[i];
#pragma unroll 4
  for (int r = 0; r < 1024; ++r) s += ow[(size_t)i * 1024 + r] * uv[r];
  bcomb[i] = s;
}

// ---------------------------------------------------------------------------
// build_xe: xe[(b*2048+t)*2+d][c] = bf16( x[b][c][d][t] + emb[d][c] )
// ---------------------------------------------------------------------------
__global__ __launch_bounds__(256)
void build_xe(const float* __restrict__ x, const float* __restrict__ emb,
              u16* __restrict__ xe) {
  __shared__ u16 tile[64][66];
  int bt = blockIdx.x;
  int tt = bt & 31, ct = (bt >> 5) & 7, d = (bt >> 8) & 1, b = bt >> 9;
  int t0 = tt * 64, c0 = ct * 64;
  int tid = threadIdx.x;
  int q = tid & 15, r = tid >> 4;
#pragma unroll
  for (int p = 0; p < 4; ++p) {
    int c = p * 16 + r;
    const float* src = x + ((size_t)((b * 512 + c0 + c) * 2 + d)) * 2048 + t0 + q * 4;
    float4 v = *(const float4*)src;
    float e = emb[d * 512 + c0 + c];
    ushort4 o; o.x = f2bf(v.x + e); o.y = f2bf(v.y + e); o.z = f2bf(v.z + e); o.w = f2bf(v.w + e);
    *(ushort4*)&tile[c][q * 4] = o;
  }
  __syncthreads();
  int cq = tid & 7, tp = tid >> 3;
  int cc0 = cq * 8;
  u16 o0[8], o1[8];
#pragma unroll
  for (int i = 0; i < 8; ++i) {
    unsigned w2 = *(const unsigned*)&tile[cc0 + i][2 * tp];
    o0[i] = (u16)(w2 & 0xffffu); o1[i] = (u16)(w2 >> 16);
  }
  size_t n = (size_t)b * 2048 + t0 + 2 * tp;
  *(uint4*)(xe + (n * 2 + d) * 512 + c0 + cc0) = pack8(o0);
  *(uint4*)(xe + ((n + 1) * 2 + d) * 512 + c0 + cc0) = pack8(o1);
}

// ---------------------------------------------------------------------------
// gemm_bt: C[M,N] = A[M,K] @ B[N,K]^T + bias; bf16 A/B, fp32 bias, fp32 acc.
// global_load_lds staging (unpadded LDS 128x64), 128x128 tile, BK=64.
// Grid: x = m-blocks (XCD spread over m), y = n-blocks.
// EPI 0: bf16 out.  EPI 1: fp32 out, transposed write to (B,C,T).
// EPI 2: bf16 out, 2x2 P-mix across device-row pairs; h = blockIdx.y.
// ---------------------------------------------------------------------------
template<int EPI>
__global__ __launch_bounds__(256, 3)
void gemm_bt(const u16* __restrict__ A, int lda,
             const u16* __restrict__ B, int ldb,
             const float* __restrict__ bias,
             void* __restrict__ Cv, int ldc, int K,
             const float* __restrict__ P) {
  __shared__ u16 As[128 * 64];
  __shared__ u16 Bs[128 * 64];
  int m0 = blockIdx.x * 128;
  int n0 = blockIdx.y * 128;
  int t = threadIdx.x;
  int lane = t & 63;
  int w = t >> 6;
  int wm = (w >> 1) * 64, wn = (w & 1) * 64;
  int l15 = lane & 15, quad = lane >> 4;

  floatx4 acc[4][4];
#pragma unroll
  for (int i = 0; i < 4; ++i)
#pragma unroll
    for (int j = 0; j < 4; ++j) acc[i][j] = (floatx4){0.f, 0.f, 0.f, 0.f};

  // staging: wave w owns rows [w*32, w*32+32); 4 issues of 8 rows each side.
  int lrow = lane >> 3, lcol = (lane & 7) * 8;
  const u16* gA = A + (size_t)(m0 + w * 32 + lrow) * lda + lcol;
  const u16* gB = B + (size_t)(n0 + w * 32 + lrow) * ldb + lcol;
  u16* lA = As + (w * 32) * 64;
  u16* lB = Bs + (w * 32) * 64;

  int KT = K >> 6;
  for (int kt = 0; kt < KT; ++kt) {
    int ko = kt * 64;
#pragma unroll
    for (int j = 0; j < 4; ++j) {
      gll16(gA + (size_t)(j * 8) * lda + ko, lA + (j * 8) * 64);
      gll16(gB + (size_t)(j * 8) * ldb + ko, lB + (j * 8) * 64);
    }
    __syncthreads();
#pragma unroll
    for (int ki = 0; ki < 2; ++ki) {
      short8 af[4], bfv[4];
#pragma unroll
      for (int i = 0; i < 4; ++i)
        af[i] = *(const short8*)&As[(wm + i * 16 + l15) * 64 + ki * 32 + quad * 8];
#pragma unroll
      for (int j = 0; j < 4; ++j)
        bfv[j] = *(const short8*)&Bs[(wn + j * 16 + l15) * 64 + ki * 32 + quad * 8];
#pragma unroll
      for (int i = 0; i < 4; ++i)
#pragma unroll
        for (int j = 0; j < 4; ++j)
          acc[i][j] = __builtin_amdgcn_mfma_f32_16x16x32_bf16(af[i], bfv[j], acc[i][j], 0, 0, 0);
    }
    __syncthreads();
  }

  // epilogue: C/D layout col = lane&15, row = quad*4 + reg  [m89-verified]
#pragma unroll
  for (int i = 0; i < 4; ++i) {
    int mrow = m0 + wm + i * 16 + quad * 4;
    float4 P0, P1;
    if (EPI == 2) {
      int np0 = mrow >> 1;
      P0 = *(const float4*)&P[((size_t)np0 * 4 + blockIdx.y) * 4];
      P1 = *(const float4*)&P[((size_t)(np0 + 1) * 4 + blockIdx.y) * 4];
    }
#pragma unroll
    for (int j = 0; j < 4; ++j) {
      int col = n0 + wn + j * 16 + l15;
      float bv = bias[col];
      floatx4 a = acc[i][j];
      if (EPI == 1) {
        int bb = mrow >> 11, ti = mrow & 2047;
        float4 o; o.x = a[0] + bv; o.y = a[1] + bv; o.z = a[2] + bv; o.w = a[3] + bv;
        *(float4*)&((float*)Cv)[((size_t)bb * ldc + col) * 2048 + ti] = o;
      } else if (EPI == 2) {
        float a0 = a[0] + bv, a1 = a[1] + bv, a2 = a[2] + bv, a3 = a[3] + bv;
        u16* C = (u16*)Cv;
        C[(size_t)(mrow + 0) * ldc + col] = f2bf(P0.x * a0 + P0.y * a1);
        C[(size_t)(mrow + 1) * ldc + col] = f2bf(P0.z * a0 + P0.w * a1);
        C[(size_t)(mrow + 2) * ldc + col] = f2bf(P1.x * a2 + P1.y * a3);
        C[(size_t)(mrow + 3) * ldc + col] = f2bf(P1.z * a2 + P1.w * a3);
      } else {
        u16* C = (u16*)Cv;
#pragma unroll
        for (int r = 0; r < 4; ++r)
          C[(size_t)(mrow + r) * ldc + col] = f2bf(a[r] + bv);
      }
    }
  }
}

// ---------------------------------------------------------------------------
// score_kernel: thread per (n,h); QK row 2n/2n+1, q at col h*128, k at 512+h*128.
// 2x2 scores -> softmax -> P[n][h][2][2] (float4) + asum block reduction.
// ---------------------------------------------------------------------------
__global__ __launch_bounds__(256)
void score_kernel(const u16* __restrict__ QK, float* __restrict__ P,
                  float* __restrict__ asum) {
  int g = blockIdx.x * 256 + threadIdx.x;
  int n = g >> 2, h = g & 3;
  const u16* q0 = QK + (size_t)(2 * n) * 1024 + h * 128;
  const u16* q1 = q0 + 1024;
  const u16* k0 = q0 + 512;
  const u16* k1 = k0 + 1024;

  float s00 = 0.f, s01 = 0.f, s10 = 0.f, s11 = 0.f;
#pragma unroll
  for (int c = 0; c < 128; c += 8) {
    float fq0[8], fq1[8], fk0[8], fk1[8];
    unpack8(*(const uint4*)(q0 + c), fq0);
    unpack8(*(const uint4*)(q1 + c), fq1);
    unpack8(*(const uint4*)(k0 + c), fk0);
    unpack8(*(const uint4*)(k1 + c), fk1);
#pragma unroll
    for (int u = 0; u < 8; ++u) {
      s00 += fq0[u] * fk0[u]; s01 += fq0[u] * fk1[u];
      s10 += fq1[u] * fk0[u]; s11 += fq1[u] * fk1[u];
    }
  }
  const float sc = 0.08838834764831845f;  // 1/sqrt(128)
  s00 *= sc; s01 *= sc; s10 *= sc; s11 *= sc;
  float m0v = fmaxf(s00, s01), m1v = fmaxf(s10, s11);
  float e00 = __expf(s00 - m0v), e01 = __expf(s01 - m0v);
  float e10 = __expf(s10 - m1v), e11 = __expf(s11 - m1v);
  float i0 = 1.f / (e00 + e01), i1 = 1.f / (e10 + e11);
  float4 p; p.x = e00 * i0; p.y = e01 * i0; p.z = e10 * i1; p.w = e11 * i1;
  *(float4*)&P[(size_t)g * 4] = p;

  float pv[4] = {p.x, p.y, p.z, p.w};
#pragma unroll
  for (int k2 = 0; k2 < 4; ++k2) {
    float v = pv[k2];
    v += __shfl_down(v, 32, 64); v += __shfl_down(v, 16, 64);
    v += __shfl_down(v, 8, 64);  v += __shfl_down(v, 4, 64);
    v += __shfl_down(v, 2, 64);  v += __shfl_down(v, 1, 64);
    pv[k2] = v;
  }
  __shared__ float red[4][4];
  int lane = threadIdx.x & 63, wv = threadIdx.x >> 6;
  if (lane == 0) { red[wv][0] = pv[0]; red[wv][1] = pv[1]; red[wv][2] = pv[2]; red[wv][3] = pv[3]; }
  __syncthreads();
  if (threadIdx.x < 4) {
    float s = red[0][threadIdx.x] + red[1][threadIdx.x] + red[2][threadIdx.x] + red[3][threadIdx.x];
    int b = (blockIdx.x * 64) >> 11;
    atomicAdd(&asum[b * 4 + threadIdx.x], s);
  }
}

__global__ void avg_kernel(const float* __restrict__ asum, float* __restrict__ out) {
  int i = threadIdx.x;  // 64 = 16 b * 4
  out[16777216 + i] = asum[i] * (1.0f / 8192.0f);  // / (H=4 * T=2048)
}

// ---------------------------------------------------------------------------
// Workspace (~206 MiB, within the 208 MiB high-water mark of round 3):
//   ctx    bf16 65536x512   @ 0           (64 MiB)
//   QK     bf16 65536x1024  @ 67108864    (128 MiB) -- prep scratch aliases
//     outwT @ 67108864, phw_bf @ 67633152, imw_bf @ 68157440,
//     ow_bf @ 68681728 (1 MiB), T1T @ 69730304, T2T @ 70254592
//     (all dead before the QK GEMM writes QK)
//   inw_bf bf16 1536x512    @ 201326592
//   Wcomb  bf16 512x1024    @ 202899456
//   uv @ 203948032, bcomb @ 203952128, P @ 203954176 (2 MiB),
//   asum @ 206051328 (256 B), zbias @ 206051584 (2 KiB)
// xe (bf16 65536x512 = 64 MiB) staged in d_out (dead before final GEMM writes).
// ---------------------------------------------------------------------------
extern "C" void kernel_launch(void* const* d_in, const int* in_sizes, int n_in,
                              void* d_out, int out_size, void* d_ws, size_t ws_size,
                              hipStream_t stream) {
  const float* x    = (const float*)d_in[0];
  const float* emb  = (const float*)d_in[1];
  const float* inw  = (const float*)d_in[2];
  const float* inb  = (const float*)d_in[3];
  const float* outw = (const float*)d_in[4];
  const float* outb = (const float*)d_in[5];
  const float* phw  = (const float*)d_in[6];
  const float* phb  = (const float*)d_in[7];
  const float* imw  = (const float*)d_in[8];
  const float* imb  = (const float*)d_in[9];
  const float* ow   = (const float*)d_in[10];
  const float* ob   = (const float*)d_in[11];
  float* outF = (float*)d_out;

  char* wsb = (char*)d_ws;
  u16*   ctx    = (u16*)wsb;
  u16*   QK     = (u16*)(wsb + 67108864);
  u16*   outwT  = (u16*)(wsb + 67108864);
  u16*   phw_bf = (u16*)(wsb + 67633152);
  u16*   imw_bf = (u16*)(wsb + 68157440);
  u16*   ow_bf  = (u16*)(wsb + 68681728);
  u16*   T1T    = (u16*)(wsb + 69730304);
  u16*   T2T    = (u16*)(wsb + 70254592);
  u16*   inw_bf = (u16*)(wsb + 201326592);
  u16*   Wcomb  = (u16*)(wsb + 202899456);
  float* uv     = (float*)(wsb + 203948032);
  float* bcomb  = (float*)(wsb + 203952128);
  float* P      = (float*)(wsb + 203954176);
  float* asum   = (float*)(wsb + 206051328);
  float* zbias  = (float*)(wsb + 206051584);
  u16*   xe     = (u16*)d_out;

  // zero asum (256 B) + zbias (2 KiB) in one memset
  hipMemsetAsync(asum, 0, 2304, stream);

  // xe = transpose(x) + emb  (bf16, staged in d_out) -- biggest prep, first
  build_xe<<<8192, 256, 0, stream>>>(x, emb, xe);

  // weight conversions (one launch), then MFMA weight-fold chain
  prep_convert<<<dim3(768, 5), 256, 0, stream>>>(inw, phw, imw, ow, outw,
                                                 inw_bf, phw_bf, imw_bf, ow_bf, outwT);
  // T1T = outwT @ phw^T ; T2T = outwT @ imw^T   (512x512x512)
  gemm_bt<0><<<dim3(4, 4), 256, 0, stream>>>(outwT, 512, phw_bf, 512, zbias, T1T, 512, 512, nullptr);
  gemm_bt<0><<<dim3(4, 4), 256, 0, stream>>>(outwT, 512, imw_bf, 512, zbias, T2T, 512, 512, nullptr);
  // Wcomb[:, :512] = ow_L @ T1 ; Wcomb[:, 512:] = ow_R @ T2
  gemm_bt<0><<<dim3(4, 4), 256, 0, stream>>>(ow_bf, 1024, T1T, 512, zbias, Wcomb, 1024, 512, nullptr);
  gemm_bt<0><<<dim3(4, 4), 256, 0, stream>>>(ow_bf + 512, 1024, T2T, 512, zbias, Wcomb + 512, 1024, 512, nullptr);
  // combined bias (fp32 path, tiny)
  uv_kernel<<<4, 256, 0, stream>>>(phw, phb, imw, imb, outb, uv);
  bcomb_kernel<<<2, 256, 0, stream>>>(ow, ob, uv, bcomb);

  // QK = xe @ [Wq;Wk]^T + [bq;bk]   (65536 x 1024 x 512)
  gemm_bt<0><<<dim3(512, 8), 256, 0, stream>>>(xe, 512, inw_bf, 512, inb,
                                               QK, 1024, 512, nullptr);
  // 2x2 softmax -> P, asum
  score_kernel<<<512, 256, 0, stream>>>(QK, P, asum);
  // V GEMM + P-mix epilogue -> ctx
  gemm_bt<2><<<dim3(512, 4), 256, 0, stream>>>(xe, 512, inw_bf + 524288, 512,
                                               inb + 1024, ctx, 512, 512, P);
  // folded tail: out = ctx(pairs, K=1024) @ Wcomb^T + bcomb, transposed (B,C,T)
  gemm_bt<1><<<dim3(256, 4), 256, 0, stream>>>(ctx, 1024, Wcomb, 1024,
                                               bcomb, outF, 512, 1024, nullptr);
  avg_kernel<<<1, 64, 0, stream>>>(asum, outF);
}